// Round 4
// baseline (6532.133 us; speedup 1.0000x reference)
//
#include <hip/hip_runtime.h>

typedef __attribute__((ext_vector_type(8))) __bf16 bf16x8;
typedef __attribute__((ext_vector_type(4))) float floatx4;

static __device__ __forceinline__ floatx4 mfma16(bf16x8 a, bf16x8 b, floatx4 c) {
  return __builtin_amdgcn_mfma_f32_16x16x32_bf16(a, b, c, 0, 0, 0);
}

static __device__ __forceinline__ unsigned short f2b_bits(float f) {
  __bf16 h = (__bf16)f;
  return __builtin_bit_cast(unsigned short, h);
}

// ---------------------------------------------------------------- cast + zero lsum
__global__ void cast_kernel(const float4* __restrict__ x, const float4* __restrict__ w,
                            ushort4* __restrict__ xb, ushort4* __restrict__ wb,
                            float* __restrict__ lsum) {
  int i = blockIdx.x * 256 + threadIdx.x;
  if (i < 4194304) {
    float4 v = x[i];
    ushort4 o;
    o.x = f2b_bits(v.x); o.y = f2b_bits(v.y); o.z = f2b_bits(v.z); o.w = f2b_bits(v.w);
    xb[i] = o;
  } else if (i < 4456448) {
    int j = i - 4194304;
    float4 v = w[j];
    ushort4 o;
    o.x = f2b_bits(v.x); o.y = f2b_bits(v.y); o.z = f2b_bits(v.z); o.w = f2b_bits(v.w);
    wb[j] = o;
  } else {
    int j = i - 4456448;
    if (j < 16384) lsum[j] = 0.0f;
  }
}

// ---------------------------------------------------------------- z^T = (x @ W^T)^T
// Barrier-free: each wave loads its own fragments global->VGPR, 2-deep ping-pong.
__global__ __launch_bounds__(256, 2) void gemm_zT(const unsigned short* __restrict__ xb,
                                                  const unsigned short* __restrict__ wb,
                                                  unsigned short* __restrict__ zT) {
  const int tid = threadIdx.x, wid = tid >> 6, lane = tid & 63;
  const int wr = wid >> 1, wc = wid & 1, lr = lane & 15, lq = lane >> 4;
  const int g = blockIdx.x;
  const int xt = g & 127, yt = g >> 7;
  const int m0 = xt * 128, n0 = yt * 128;

  floatx4 acc[4][4] = {};
  const unsigned short* gA = xb + (m0 + wr * 64 + lr) * 1024 + lq * 8;  // +i*16 rows
  const unsigned short* gB = wb + (n0 + wc * 64 + lr) * 1024 + lq * 8;  // +j*16 rows

  bf16x8 aR[2][4], bR[2][4];
#pragma unroll
  for (int i = 0; i < 4; ++i) aR[0][i] = *(const bf16x8*)(gA + i * 16 * 1024);
#pragma unroll
  for (int j = 0; j < 4; ++j) bR[0][j] = *(const bf16x8*)(gB + j * 16 * 1024);

  for (int it = 0; it < 32; ++it) {
    const int cur = it & 1, nxt = cur ^ 1;
    if (it + 1 < 32) {
      const int k = (it + 1) * 32;
#pragma unroll
      for (int i = 0; i < 4; ++i) aR[nxt][i] = *(const bf16x8*)(gA + i * 16 * 1024 + k);
#pragma unroll
      for (int j = 0; j < 4; ++j) bR[nxt][j] = *(const bf16x8*)(gB + j * 16 * 1024 + k);
    }
#pragma unroll
    for (int i = 0; i < 4; ++i)
#pragma unroll
      for (int j = 0; j < 4; ++j) acc[i][j] = mfma16(aR[cur][i], bR[cur][j], acc[i][j]);
  }

  const int bb = m0 >> 11, sb = m0 & 2047;
#pragma unroll
  for (int i = 0; i < 4; ++i) {
    const int srow = sb + wr * 64 + i * 16 + lq * 4;
#pragma unroll
    for (int j = 0; j < 4; ++j) {
      const int n = n0 + wc * 64 + j * 16 + lr;
      ushort4 o;
      o.x = f2b_bits(acc[i][j][0]); o.y = f2b_bits(acc[i][j][1]);
      o.z = f2b_bits(acc[i][j][2]); o.w = f2b_bits(acc[i][j][3]);
      *(ushort4*)(zT + (((size_t)(bb << 10) | n) * 2048 + srow)) = o;
    }
  }
}

// ---------------------------------------------------------------- QK^T + exp epilogue
__global__ __launch_bounds__(256, 2) void qk_exp(const unsigned short* __restrict__ xb,
                                                 unsigned short* __restrict__ P,
                                                 float* __restrict__ lsum) {
  const int tid = threadIdx.x, wid = tid >> 6, lane = tid & 63;
  const int wr = wid >> 1, wc = wid & 1, lr = lane & 15, lq = lane >> 4;
  const int t = blockIdx.x, b = t & 7, idx = t >> 3;
  int mt = (int)((sqrtf(8.0f * idx + 1.0f) - 1.0f) * 0.5f);
  while ((mt + 1) * (mt + 2) / 2 <= idx) ++mt;
  while (mt * (mt + 1) / 2 > idx) --mt;
  const int nt = idx - mt * (mt + 1) / 2;
  const unsigned short* xbb = xb + (size_t)b * (2048 * 1024);
  const int q0 = mt * 128, k0t = nt * 128;

  floatx4 acc[4][4] = {};
  const unsigned short* gA = xbb + (q0 + wr * 64 + lr) * 1024 + lq * 8;
  const unsigned short* gB = xbb + (k0t + wc * 64 + lr) * 1024 + lq * 8;

  bf16x8 aR[2][4], bR[2][4];
#pragma unroll
  for (int i = 0; i < 4; ++i) aR[0][i] = *(const bf16x8*)(gA + i * 16 * 1024);
#pragma unroll
  for (int j = 0; j < 4; ++j) bR[0][j] = *(const bf16x8*)(gB + j * 16 * 1024);

  for (int it = 0; it < 32; ++it) {
    const int cur = it & 1, nxt = cur ^ 1;
    if (it + 1 < 32) {
      const int k = (it + 1) * 32;
#pragma unroll
      for (int i = 0; i < 4; ++i) aR[nxt][i] = *(const bf16x8*)(gA + i * 16 * 1024 + k);
#pragma unroll
      for (int j = 0; j < 4; ++j) bR[nxt][j] = *(const bf16x8*)(gB + j * 16 * 1024 + k);
    }
#pragma unroll
    for (int i = 0; i < 4; ++i)
#pragma unroll
      for (int j = 0; j < 4; ++j) acc[i][j] = mfma16(aR[cur][i], bR[cur][j], acc[i][j]);
  }

  unsigned short* Pt = P + ((size_t)b * 136 + (size_t)(mt * (mt + 1) / 2 + nt)) * 16384;
  const bool diag = (mt == nt);
#pragma unroll
  for (int i = 0; i < 4; ++i) {
    const int row_l = wr * 64 + i * 16 + lq * 4;
    floatx4 rs = {0.0f, 0.0f, 0.0f, 0.0f};
#pragma unroll
    for (int j = 0; j < 4; ++j) {
      const int col_l = wc * 64 + j * 16 + lr;
#pragma unroll
      for (int v = 0; v < 4; ++v) {
        float p = __expf(acc[i][j][v] * 0.03125f - 44.0f);
        if (diag && col_l > row_l + v) p = 0.0f;
        Pt[(row_l + v) * 128 + col_l] = f2b_bits(p);
        rs[v] += p;
      }
    }
#pragma unroll
    for (int v = 0; v < 4; ++v) {
      float s = rs[v];
      s += __shfl_xor(s, 1);
      s += __shfl_xor(s, 2);
      s += __shfl_xor(s, 4);
      s += __shfl_xor(s, 8);
      if (lr == 0) atomicAdd(&lsum[b * 2048 + q0 + row_l + v], s);
    }
  }
}

// ---------------------------------------------------------------- O = P @ z, divide by lsum
__global__ __launch_bounds__(256, 2) void pv_out(const unsigned short* __restrict__ P,
                                                 const unsigned short* __restrict__ zT,
                                                 const float* __restrict__ lsum,
                                                 float* __restrict__ out) {
  const int tid = threadIdx.x, wid = tid >> 6, lane = tid & 63;
  const int wr = wid >> 1, wc = wid & 1, lr = lane & 15, lq = lane >> 4;
  const int g = blockIdx.x, b = g & 7, gg = g >> 3;
  const int mt = 15 - (gg >> 3), ntile = gg & 7;   // long k-loops dispatched first
  const int q0 = mt * 128, n0 = ntile * 128;
  const unsigned short* Pb = P + (size_t)b * 136 * 16384;
  const unsigned short* zTb = zT + (size_t)b * 1024 * 2048;
  const int tri = mt * (mt + 1) / 2;
  const int ktot = (mt + 1) * 4;  // BK=32 steps

  floatx4 acc[4][4] = {};
  // A (P tiles): frag addr = base + (kk>>2)*16384 + (kk&3)*32 ; rowgroup stride 16*128
  const unsigned short* gA = Pb + (size_t)tri * 16384 + (wr * 64 + lr) * 128 + lq * 8;
  // B (zT): keys contiguous; rowgroup stride 16*2048
  const unsigned short* gB = zTb + (n0 + wc * 64 + lr) * 2048 + lq * 8;

  bf16x8 aR[2][4], bR[2][4];
#pragma unroll
  for (int i = 0; i < 4; ++i) aR[0][i] = *(const bf16x8*)(gA + i * 16 * 128);
#pragma unroll
  for (int j = 0; j < 4; ++j) bR[0][j] = *(const bf16x8*)(gB + j * 16 * 2048);

  for (int kk = 0; kk < ktot; ++kk) {
    const int cur = kk & 1, nxt = cur ^ 1;
    if (kk + 1 < ktot) {
      const int nk = kk + 1;
      const int aoff = (nk >> 2) * 16384 + (nk & 3) * 32;
      const int boff = nk * 32;
#pragma unroll
      for (int i = 0; i < 4; ++i) aR[nxt][i] = *(const bf16x8*)(gA + aoff + i * 16 * 128);
#pragma unroll
      for (int j = 0; j < 4; ++j) bR[nxt][j] = *(const bf16x8*)(gB + boff + j * 16 * 2048);
    }
#pragma unroll
    for (int i = 0; i < 4; ++i)
#pragma unroll
      for (int j = 0; j < 4; ++j) acc[i][j] = mfma16(aR[cur][i], bR[cur][j], acc[i][j]);
  }

  float* outb = out + (size_t)b * 2048 * 1024;
#pragma unroll
  for (int i = 0; i < 4; ++i) {
    const int row_l = wr * 64 + i * 16 + lq * 4;
    floatx4 linv;
#pragma unroll
    for (int v = 0; v < 4; ++v) linv[v] = 1.0f / lsum[b * 2048 + q0 + row_l + v];
#pragma unroll
    for (int j = 0; j < 4; ++j) {
      const int col = n0 + wc * 64 + j * 16 + lr;
#pragma unroll
      for (int v = 0; v < 4; ++v)
        outb[(size_t)(q0 + row_l + v) * 1024 + col] = acc[i][j][v] * linv[v];
    }
  }
}

// ---------------------------------------------------------------- launcher
extern "C" void kernel_launch(void* const* d_in, const int* in_sizes, int n_in,
                              void* d_out, int out_size, void* d_ws, size_t ws_size,
                              hipStream_t stream) {
  const float* x = (const float*)d_in[0];  // [8][2048][1024]
  const float* W = (const float*)d_in[1];  // [1024][1024]
  float* out = (float*)d_out;              // [8][2048][1024]
  char* ws = (char*)d_ws;
  unsigned short* xb = (unsigned short*)ws;                          // 32 MiB bf16 x
  unsigned short* zT = (unsigned short*)(ws + 33554432ull);          // 32 MiB bf16 z^T
  unsigned short* P  = (unsigned short*)(ws + 67108864ull);          // 34 MiB packed tri P
  unsigned short* wb = P;  // alias: wb consumed by gemm_zT before P is written
  float* lsum = (float*)(ws + 67108864ull + 35651584ull);            // 64 KiB row sums

  cast_kernel<<<17472, 256, 0, stream>>>((const float4*)x, (const float4*)W,
                                         (ushort4*)xb, (ushort4*)wb, lsum);
  gemm_zT<<<1024, 256, 0, stream>>>(xb, wb, zT);
  qk_exp<<<1088, 256, 0, stream>>>(xb, P, lsum);
  pv_out<<<1024, 256, 0, stream>>>(P, zT, lsum, out);
}

// Round 5
// 532.317 us; speedup vs baseline: 12.2711x; 12.2711x over previous
//
#include <hip/hip_runtime.h>

typedef __attribute__((ext_vector_type(8))) __bf16 bf16x8;
typedef __attribute__((ext_vector_type(4))) float floatx4;

static __device__ __forceinline__ floatx4 mfma16(bf16x8 a, bf16x8 b, floatx4 c) {
  return __builtin_amdgcn_mfma_f32_16x16x32_bf16(a, b, c, 0, 0, 0);
}

static __device__ __forceinline__ unsigned short f2b_bits(float f) {
  __bf16 h = (__bf16)f;
  return __builtin_bit_cast(unsigned short, h);
}

// ---------------------------------------------------------------- cast + zero lsum
__global__ void cast_kernel(const float4* __restrict__ x, const float4* __restrict__ w,
                            ushort4* __restrict__ xb, ushort4* __restrict__ wb,
                            float* __restrict__ lsum) {
  int i = blockIdx.x * 256 + threadIdx.x;
  if (i < 4194304) {
    float4 v = x[i];
    ushort4 o;
    o.x = f2b_bits(v.x); o.y = f2b_bits(v.y); o.z = f2b_bits(v.z); o.w = f2b_bits(v.w);
    xb[i] = o;
  } else if (i < 4456448) {
    int j = i - 4194304;
    float4 v = w[j];
    ushort4 o;
    o.x = f2b_bits(v.x); o.y = f2b_bits(v.y); o.z = f2b_bits(v.z); o.w = f2b_bits(v.w);
    wb[j] = o;
  } else {
    int j = i - 4456448;
    if (j < 16384) lsum[j] = 0.0f;
  }
}

// ---------------------------------------------------------------- z^T = (x @ W^T)^T
// Barrier-free register-direct; compile-time K-loop (fully unrolled -> static regs).
__global__ __launch_bounds__(256, 2) void gemm_zT(const unsigned short* __restrict__ xb,
                                                  const unsigned short* __restrict__ wb,
                                                  unsigned short* __restrict__ zT) {
  const int tid = threadIdx.x, wid = tid >> 6, lane = tid & 63;
  const int wr = wid >> 1, wc = wid & 1, lr = lane & 15, lq = lane >> 4;
  const int g = blockIdx.x;
  const int xt = g & 127, yt = g >> 7;
  const int m0 = xt * 128, n0 = yt * 128;

  floatx4 acc[4][4] = {};
  const unsigned short* gA = xb + (m0 + wr * 64 + lr) * 1024 + lq * 8;
  const unsigned short* gB = wb + (n0 + wc * 64 + lr) * 1024 + lq * 8;

  bf16x8 aR[2][4], bR[2][4];
#pragma unroll
  for (int i = 0; i < 4; ++i) aR[0][i] = *(const bf16x8*)(gA + i * 16 * 1024);
#pragma unroll
  for (int j = 0; j < 4; ++j) bR[0][j] = *(const bf16x8*)(gB + j * 16 * 1024);

#pragma unroll
  for (int it = 0; it < 32; ++it) {
    const int cur = it & 1, nxt = cur ^ 1;
    if (it + 1 < 32) {
      const int k = (it + 1) * 32;
#pragma unroll
      for (int i = 0; i < 4; ++i) aR[nxt][i] = *(const bf16x8*)(gA + i * 16 * 1024 + k);
#pragma unroll
      for (int j = 0; j < 4; ++j) bR[nxt][j] = *(const bf16x8*)(gB + j * 16 * 1024 + k);
    }
#pragma unroll
    for (int i = 0; i < 4; ++i)
#pragma unroll
      for (int j = 0; j < 4; ++j) acc[i][j] = mfma16(aR[cur][i], bR[cur][j], acc[i][j]);
  }

  const int bb = m0 >> 11, sb = m0 & 2047;
#pragma unroll
  for (int i = 0; i < 4; ++i) {
    const int srow = sb + wr * 64 + i * 16 + lq * 4;
#pragma unroll
    for (int j = 0; j < 4; ++j) {
      const int n = n0 + wc * 64 + j * 16 + lr;
      ushort4 o;
      o.x = f2b_bits(acc[i][j][0]); o.y = f2b_bits(acc[i][j][1]);
      o.z = f2b_bits(acc[i][j][2]); o.w = f2b_bits(acc[i][j][3]);
      *(ushort4*)(zT + (((size_t)(bb << 10) | n) * 2048 + srow)) = o;
    }
  }
}

// ---------------------------------------------------------------- QK^T + exp epilogue
__global__ __launch_bounds__(256, 2) void qk_exp(const unsigned short* __restrict__ xb,
                                                 unsigned short* __restrict__ P,
                                                 float* __restrict__ lsum) {
  const int tid = threadIdx.x, wid = tid >> 6, lane = tid & 63;
  const int wr = wid >> 1, wc = wid & 1, lr = lane & 15, lq = lane >> 4;
  const int t = blockIdx.x, b = t & 7, idx = t >> 3;
  int mt = (int)((sqrtf(8.0f * idx + 1.0f) - 1.0f) * 0.5f);
  while ((mt + 1) * (mt + 2) / 2 <= idx) ++mt;
  while (mt * (mt + 1) / 2 > idx) --mt;
  const int nt = idx - mt * (mt + 1) / 2;
  const unsigned short* xbb = xb + (size_t)b * (2048 * 1024);
  const int q0 = mt * 128, k0t = nt * 128;

  floatx4 acc[4][4] = {};
  const unsigned short* gA = xbb + (q0 + wr * 64 + lr) * 1024 + lq * 8;
  const unsigned short* gB = xbb + (k0t + wc * 64 + lr) * 1024 + lq * 8;

  bf16x8 aR[2][4], bR[2][4];
#pragma unroll
  for (int i = 0; i < 4; ++i) aR[0][i] = *(const bf16x8*)(gA + i * 16 * 1024);
#pragma unroll
  for (int j = 0; j < 4; ++j) bR[0][j] = *(const bf16x8*)(gB + j * 16 * 1024);

#pragma unroll
  for (int it = 0; it < 32; ++it) {
    const int cur = it & 1, nxt = cur ^ 1;
    if (it + 1 < 32) {
      const int k = (it + 1) * 32;
#pragma unroll
      for (int i = 0; i < 4; ++i) aR[nxt][i] = *(const bf16x8*)(gA + i * 16 * 1024 + k);
#pragma unroll
      for (int j = 0; j < 4; ++j) bR[nxt][j] = *(const bf16x8*)(gB + j * 16 * 1024 + k);
    }
#pragma unroll
    for (int i = 0; i < 4; ++i)
#pragma unroll
      for (int j = 0; j < 4; ++j) acc[i][j] = mfma16(aR[cur][i], bR[cur][j], acc[i][j]);
  }

  unsigned short* Pt = P + ((size_t)b * 136 + (size_t)(mt * (mt + 1) / 2 + nt)) * 16384;
  const bool diag = (mt == nt);
#pragma unroll
  for (int i = 0; i < 4; ++i) {
    const int row_l = wr * 64 + i * 16 + lq * 4;
    floatx4 rs = {0.0f, 0.0f, 0.0f, 0.0f};
#pragma unroll
    for (int j = 0; j < 4; ++j) {
      const int col_l = wc * 64 + j * 16 + lr;
#pragma unroll
      for (int v = 0; v < 4; ++v) {
        float p = __expf(acc[i][j][v] * 0.03125f - 44.0f);
        if (diag && col_l > row_l + v) p = 0.0f;
        Pt[(row_l + v) * 128 + col_l] = f2b_bits(p);
        rs[v] += p;
      }
    }
#pragma unroll
    for (int v = 0; v < 4; ++v) {
      float s = rs[v];
      s += __shfl_xor(s, 1);
      s += __shfl_xor(s, 2);
      s += __shfl_xor(s, 4);
      s += __shfl_xor(s, 8);
      if (lr == 0) atomicAdd(&lsum[b * 2048 + q0 + row_l + v], s);
    }
  }
}

// ---------------------------------------------------------------- O = P @ z, divide by lsum
// Runtime trip count -> manual unroll-by-2 with STATICALLY-NAMED double buffers
// (dynamic parity indexing demoted the buffers to scratch in R4: 1.57 GB spill traffic).
__global__ __launch_bounds__(256, 2) void pv_out(const unsigned short* __restrict__ P,
                                                 const unsigned short* __restrict__ zT,
                                                 const float* __restrict__ lsum,
                                                 float* __restrict__ out) {
  const int tid = threadIdx.x, wid = tid >> 6, lane = tid & 63;
  const int wr = wid >> 1, wc = wid & 1, lr = lane & 15, lq = lane >> 4;
  const int g = blockIdx.x, b = g & 7, gg = g >> 3;
  const int mt = 15 - (gg >> 3), ntile = gg & 7;   // long k-loops dispatched first
  const int q0 = mt * 128, n0 = ntile * 128;
  const unsigned short* Pb = P + (size_t)b * 136 * 16384;
  const unsigned short* zTb = zT + (size_t)b * 1024 * 2048;
  const int tri = mt * (mt + 1) / 2;
  const int ktot = (mt + 1) * 4;  // BK=32 steps; always a multiple of 4 (even)

  floatx4 acc[4][4] = {};
  // A (P tiles): step nk -> offset (nk>>2)*16384 + (nk&3)*32 ; rowgroup stride 16*128
  const unsigned short* gA = Pb + (size_t)tri * 16384 + (wr * 64 + lr) * 128 + lq * 8;
  // B (zT): keys contiguous -> offset nk*32 ; rowgroup stride 16*2048
  const unsigned short* gB = zTb + (n0 + wc * 64 + lr) * 2048 + lq * 8;

  bf16x8 a0[4], b0[4], a1[4], b1[4];
#pragma unroll
  for (int i = 0; i < 4; ++i) a0[i] = *(const bf16x8*)(gA + i * 16 * 128);
#pragma unroll
  for (int j = 0; j < 4; ++j) b0[j] = *(const bf16x8*)(gB + j * 16 * 2048);

  for (int kk = 0; kk < ktot; kk += 2) {
    {  // prefetch kk+1 into buf1 (kk+1 < ktot always: ktot even)
      const int nk = kk + 1;
      const int aoff = (nk >> 2) * 16384 + (nk & 3) * 32;
      const int boff = nk * 32;
#pragma unroll
      for (int i = 0; i < 4; ++i) a1[i] = *(const bf16x8*)(gA + aoff + i * 16 * 128);
#pragma unroll
      for (int j = 0; j < 4; ++j) b1[j] = *(const bf16x8*)(gB + boff + j * 16 * 2048);
    }
#pragma unroll
    for (int i = 0; i < 4; ++i)
#pragma unroll
      for (int j = 0; j < 4; ++j) acc[i][j] = mfma16(a0[i], b0[j], acc[i][j]);
    if (kk + 2 < ktot) {  // prefetch kk+2 into buf0
      const int nk = kk + 2;
      const int aoff = (nk >> 2) * 16384 + (nk & 3) * 32;
      const int boff = nk * 32;
#pragma unroll
      for (int i = 0; i < 4; ++i) a0[i] = *(const bf16x8*)(gA + aoff + i * 16 * 128);
#pragma unroll
      for (int j = 0; j < 4; ++j) b0[j] = *(const bf16x8*)(gB + boff + j * 16 * 2048);
    }
#pragma unroll
    for (int i = 0; i < 4; ++i)
#pragma unroll
      for (int j = 0; j < 4; ++j) acc[i][j] = mfma16(a1[i], b1[j], acc[i][j]);
  }

  float* outb = out + (size_t)b * 2048 * 1024;
#pragma unroll
  for (int i = 0; i < 4; ++i) {
    const int row_l = wr * 64 + i * 16 + lq * 4;
    floatx4 linv;
#pragma unroll
    for (int v = 0; v < 4; ++v) linv[v] = 1.0f / lsum[b * 2048 + q0 + row_l + v];
#pragma unroll
    for (int j = 0; j < 4; ++j) {
      const int col = n0 + wc * 64 + j * 16 + lr;
#pragma unroll
      for (int v = 0; v < 4; ++v)
        outb[(size_t)(q0 + row_l + v) * 1024 + col] = acc[i][j][v] * linv[v];
    }
  }
}

// ---------------------------------------------------------------- launcher
extern "C" void kernel_launch(void* const* d_in, const int* in_sizes, int n_in,
                              void* d_out, int out_size, void* d_ws, size_t ws_size,
                              hipStream_t stream) {
  const float* x = (const float*)d_in[0];  // [8][2048][1024]
  const float* W = (const float*)d_in[1];  // [1024][1024]
  float* out = (float*)d_out;              // [8][2048][1024]
  char* ws = (char*)d_ws;
  unsigned short* xb = (unsigned short*)ws;                          // 32 MiB bf16 x
  unsigned short* zT = (unsigned short*)(ws + 33554432ull);          // 32 MiB bf16 z^T
  unsigned short* P  = (unsigned short*)(ws + 67108864ull);          // 34 MiB packed tri P
  unsigned short* wb = P;  // alias: wb consumed by gemm_zT before P is written
  float* lsum = (float*)(ws + 67108864ull + 35651584ull);            // 64 KiB row sums

  cast_kernel<<<17472, 256, 0, stream>>>((const float4*)x, (const float4*)W,
                                         (ushort4*)xb, (ushort4*)wb, lsum);
  gemm_zT<<<1024, 256, 0, stream>>>(xb, wb, zT);
  qk_exp<<<1088, 256, 0, stream>>>(xb, P, lsum);
  pv_out<<<1024, 256, 0, stream>>>(P, zT, lsum, out);
}

// Round 6
// 512.632 us; speedup vs baseline: 12.7423x; 1.0384x over previous
//
#include <hip/hip_runtime.h>

typedef __attribute__((ext_vector_type(8))) __bf16 bf16x8;
typedef __attribute__((ext_vector_type(4))) float floatx4;

static __device__ __forceinline__ floatx4 mfma16(bf16x8 a, bf16x8 b, floatx4 c) {
  return __builtin_amdgcn_mfma_f32_16x16x32_bf16(a, b, c, 0, 0, 0);
}

static __device__ __forceinline__ unsigned short f2b_bits(float f) {
  __bf16 h = (__bf16)f;
  return __builtin_bit_cast(unsigned short, h);
}

// ---------------------------------------------------------------- cast + zero lsum
__global__ void cast_kernel(const float4* __restrict__ x, const float4* __restrict__ w,
                            ushort4* __restrict__ xb, ushort4* __restrict__ wb,
                            float* __restrict__ lsum) {
  int i = blockIdx.x * 256 + threadIdx.x;
  if (i < 4194304) {
    float4 v = x[i];
    ushort4 o;
    o.x = f2b_bits(v.x); o.y = f2b_bits(v.y); o.z = f2b_bits(v.z); o.w = f2b_bits(v.w);
    xb[i] = o;
  } else if (i < 4456448) {
    int j = i - 4194304;
    float4 v = w[j];
    ushort4 o;
    o.x = f2b_bits(v.x); o.y = f2b_bits(v.y); o.z = f2b_bits(v.z); o.w = f2b_bits(v.w);
    wb[j] = o;
  } else {
    int j = i - 4456448;
    if (j < 16384) lsum[j] = 0.0f;
  }
}

// ---------------------------------------------------------------- z^T = (x @ W^T)^T
// Barrier-free register-direct, 4-buffer pipeline (depth-3 prefetch ahead).
__global__ __launch_bounds__(256, 2) void gemm_zT(const unsigned short* __restrict__ xb,
                                                  const unsigned short* __restrict__ wb,
                                                  unsigned short* __restrict__ zT) {
  const int tid = threadIdx.x, wid = tid >> 6, lane = tid & 63;
  const int wr = wid >> 1, wc = wid & 1, lr = lane & 15, lq = lane >> 4;
  const int g = blockIdx.x;
  const int xt = g & 127, yt = g >> 7;
  const int m0 = xt * 128, n0 = yt * 128;

  floatx4 acc[4][4] = {};
  const unsigned short* gA = xb + (m0 + wr * 64 + lr) * 1024 + lq * 8;
  const unsigned short* gB = wb + (n0 + wc * 64 + lr) * 1024 + lq * 8;

  bf16x8 aR[4][4], bR[4][4];
#pragma unroll
  for (int p = 0; p < 3; ++p) {
#pragma unroll
    for (int i = 0; i < 4; ++i) aR[p][i] = *(const bf16x8*)(gA + i * 16 * 1024 + p * 32);
#pragma unroll
    for (int j = 0; j < 4; ++j) bR[p][j] = *(const bf16x8*)(gB + j * 16 * 1024 + p * 32);
  }

#pragma unroll
  for (int it = 0; it < 32; ++it) {
    const int cur = it & 3;
    if (it + 3 < 32) {
      const int nb = (it + 3) & 3, k = (it + 3) * 32;
#pragma unroll
      for (int i = 0; i < 4; ++i) aR[nb][i] = *(const bf16x8*)(gA + i * 16 * 1024 + k);
#pragma unroll
      for (int j = 0; j < 4; ++j) bR[nb][j] = *(const bf16x8*)(gB + j * 16 * 1024 + k);
    }
#pragma unroll
    for (int i = 0; i < 4; ++i)
#pragma unroll
      for (int j = 0; j < 4; ++j) acc[i][j] = mfma16(aR[cur][i], bR[cur][j], acc[i][j]);
  }

  const int bb = m0 >> 11, sb = m0 & 2047;
#pragma unroll
  for (int i = 0; i < 4; ++i) {
    const int srow = sb + wr * 64 + i * 16 + lq * 4;
#pragma unroll
    for (int j = 0; j < 4; ++j) {
      const int n = n0 + wc * 64 + j * 16 + lr;
      ushort4 o;
      o.x = f2b_bits(acc[i][j][0]); o.y = f2b_bits(acc[i][j][1]);
      o.z = f2b_bits(acc[i][j][2]); o.w = f2b_bits(acc[i][j][3]);
      *(ushort4*)(zT + (((size_t)(bb << 10) | n) * 2048 + srow)) = o;
    }
  }
}

// ---------------------------------------------------------------- QK^T + exp epilogue
__global__ __launch_bounds__(256, 2) void qk_exp(const unsigned short* __restrict__ xb,
                                                 unsigned short* __restrict__ P,
                                                 float* __restrict__ lsum) {
  const int tid = threadIdx.x, wid = tid >> 6, lane = tid & 63;
  const int wr = wid >> 1, wc = wid & 1, lr = lane & 15, lq = lane >> 4;
  const int t = blockIdx.x, b = t & 7, idx = t >> 3;
  int mt = (int)((sqrtf(8.0f * idx + 1.0f) - 1.0f) * 0.5f);
  while ((mt + 1) * (mt + 2) / 2 <= idx) ++mt;
  while (mt * (mt + 1) / 2 > idx) --mt;
  const int nt = idx - mt * (mt + 1) / 2;
  const unsigned short* xbb = xb + (size_t)b * (2048 * 1024);
  const int q0 = mt * 128, k0t = nt * 128;

  floatx4 acc[4][4] = {};
  const unsigned short* gA = xbb + (q0 + wr * 64 + lr) * 1024 + lq * 8;
  const unsigned short* gB = xbb + (k0t + wc * 64 + lr) * 1024 + lq * 8;

  bf16x8 aR[4][4], bR[4][4];
#pragma unroll
  for (int p = 0; p < 3; ++p) {
#pragma unroll
    for (int i = 0; i < 4; ++i) aR[p][i] = *(const bf16x8*)(gA + i * 16 * 1024 + p * 32);
#pragma unroll
    for (int j = 0; j < 4; ++j) bR[p][j] = *(const bf16x8*)(gB + j * 16 * 1024 + p * 32);
  }

#pragma unroll
  for (int it = 0; it < 32; ++it) {
    const int cur = it & 3;
    if (it + 3 < 32) {
      const int nb = (it + 3) & 3, k = (it + 3) * 32;
#pragma unroll
      for (int i = 0; i < 4; ++i) aR[nb][i] = *(const bf16x8*)(gA + i * 16 * 1024 + k);
#pragma unroll
      for (int j = 0; j < 4; ++j) bR[nb][j] = *(const bf16x8*)(gB + j * 16 * 1024 + k);
    }
#pragma unroll
    for (int i = 0; i < 4; ++i)
#pragma unroll
      for (int j = 0; j < 4; ++j) acc[i][j] = mfma16(aR[cur][i], bR[cur][j], acc[i][j]);
  }

  unsigned short* Pt = P + ((size_t)b * 136 + (size_t)(mt * (mt + 1) / 2 + nt)) * 16384;
  const bool diag = (mt == nt);
#pragma unroll
  for (int i = 0; i < 4; ++i) {
    const int row_l = wr * 64 + i * 16 + lq * 4;
    floatx4 rs = {0.0f, 0.0f, 0.0f, 0.0f};
#pragma unroll
    for (int j = 0; j < 4; ++j) {
      const int col_l = wc * 64 + j * 16 + lr;
#pragma unroll
      for (int v = 0; v < 4; ++v) {
        float p = __expf(acc[i][j][v] * 0.03125f - 44.0f);
        if (diag && col_l > row_l + v) p = 0.0f;
        Pt[(row_l + v) * 128 + col_l] = f2b_bits(p);
        rs[v] += p;
      }
    }
#pragma unroll
    for (int v = 0; v < 4; ++v) {
      float s = rs[v];
      s += __shfl_xor(s, 1);
      s += __shfl_xor(s, 2);
      s += __shfl_xor(s, 4);
      s += __shfl_xor(s, 8);
      if (lr == 0) atomicAdd(&lsum[b * 2048 + q0 + row_l + v], s);
    }
  }
}

// ---------------------------------------------------------------- O = P @ z, divide by lsum
// Runtime trip count -> unroll-by-4 with statically-named 4-buffer rotation (depth-3).
#define PV_LOAD(abuf, bbuf, nk)                                                        \
  do {                                                                                 \
    const int aoff_ = ((nk) >> 2) * 16384 + ((nk) & 3) * 32;                           \
    const int boff_ = (nk) * 32;                                                       \
    _Pragma("unroll") for (int i_ = 0; i_ < 4; ++i_)                                   \
        abuf[i_] = *(const bf16x8*)(gA + aoff_ + i_ * 16 * 128);                       \
    _Pragma("unroll") for (int j_ = 0; j_ < 4; ++j_)                                   \
        bbuf[j_] = *(const bf16x8*)(gB + boff_ + j_ * 16 * 2048);                      \
  } while (0)

#define PV_MFMA(abuf, bbuf)                                                            \
  do {                                                                                 \
    _Pragma("unroll") for (int i_ = 0; i_ < 4; ++i_)                                   \
        _Pragma("unroll") for (int j_ = 0; j_ < 4; ++j_)                               \
            acc[i_][j_] = mfma16(abuf[i_], bbuf[j_], acc[i_][j_]);                     \
  } while (0)

__global__ __launch_bounds__(256, 2) void pv_out(const unsigned short* __restrict__ P,
                                                 const unsigned short* __restrict__ zT,
                                                 const float* __restrict__ lsum,
                                                 float* __restrict__ out) {
  const int tid = threadIdx.x, wid = tid >> 6, lane = tid & 63;
  const int wr = wid >> 1, wc = wid & 1, lr = lane & 15, lq = lane >> 4;
  const int g = blockIdx.x, b = g & 7, gg = g >> 3;
  const int mt = 15 - (gg >> 3), ntile = gg & 7;   // long k-loops dispatched first
  const int q0 = mt * 128, n0 = ntile * 128;
  const unsigned short* Pb = P + (size_t)b * 136 * 16384;
  const unsigned short* zTb = zT + (size_t)b * 1024 * 2048;
  const int tri = mt * (mt + 1) / 2;
  const int ktot = (mt + 1) * 4;  // BK=32 steps; multiple of 4

  floatx4 acc[4][4] = {};
  const unsigned short* gA = Pb + (size_t)tri * 16384 + (wr * 64 + lr) * 128 + lq * 8;
  const unsigned short* gB = zTb + (n0 + wc * 64 + lr) * 2048 + lq * 8;

  bf16x8 a0[4], b0[4], a1[4], b1[4], a2[4], b2[4], a3[4], b3[4];
  PV_LOAD(a0, b0, 0);
  PV_LOAD(a1, b1, 1);
  PV_LOAD(a2, b2, 2);

  for (int kk = 0; kk < ktot; kk += 4) {
    PV_LOAD(a3, b3, kk + 3);  // kk+3 <= ktot-1 always
    PV_MFMA(a0, b0);
    if (kk + 4 < ktot) PV_LOAD(a0, b0, kk + 4);
    PV_MFMA(a1, b1);
    if (kk + 5 < ktot) PV_LOAD(a1, b1, kk + 5);
    PV_MFMA(a2, b2);
    if (kk + 6 < ktot) PV_LOAD(a2, b2, kk + 6);
    PV_MFMA(a3, b3);
  }

  float* outb = out + (size_t)b * 2048 * 1024;
#pragma unroll
  for (int i = 0; i < 4; ++i) {
    const int row_l = wr * 64 + i * 16 + lq * 4;
    floatx4 linv;
#pragma unroll
    for (int v = 0; v < 4; ++v) linv[v] = 1.0f / lsum[b * 2048 + q0 + row_l + v];
#pragma unroll
    for (int j = 0; j < 4; ++j) {
      const int col = n0 + wc * 64 + j * 16 + lr;
#pragma unroll
      for (int v = 0; v < 4; ++v)
        outb[(size_t)(q0 + row_l + v) * 1024 + col] = acc[i][j][v] * linv[v];
    }
  }
}

// ---------------------------------------------------------------- launcher
extern "C" void kernel_launch(void* const* d_in, const int* in_sizes, int n_in,
                              void* d_out, int out_size, void* d_ws, size_t ws_size,
                              hipStream_t stream) {
  const float* x = (const float*)d_in[0];  // [8][2048][1024]
  const float* W = (const float*)d_in[1];  // [1024][1024]
  float* out = (float*)d_out;              // [8][2048][1024]
  char* ws = (char*)d_ws;
  unsigned short* xb = (unsigned short*)ws;                          // 32 MiB bf16 x
  unsigned short* zT = (unsigned short*)(ws + 33554432ull);          // 32 MiB bf16 z^T
  unsigned short* P  = (unsigned short*)(ws + 67108864ull);          // 34 MiB packed tri P
  unsigned short* wb = P;  // alias: wb consumed by gemm_zT before P is written
  float* lsum = (float*)(ws + 67108864ull + 35651584ull);            // 64 KiB row sums

  cast_kernel<<<17472, 256, 0, stream>>>((const float4*)x, (const float4*)W,
                                         (ushort4*)xb, (ushort4*)wb, lsum);
  gemm_zT<<<1024, 256, 0, stream>>>(xb, wb, zT);
  qk_exp<<<1088, 256, 0, stream>>>(xb, P, lsum);
  pv_out<<<1024, 256, 0, stream>>>(P, zT, lsum, out);
}

// Round 7
// 334.881 us; speedup vs baseline: 19.5058x; 1.5308x over previous
//
#include <hip/hip_runtime.h>

typedef __attribute__((ext_vector_type(8))) __bf16 bf16x8;
typedef __attribute__((ext_vector_type(4))) float floatx4;

static __device__ __forceinline__ floatx4 mfma16(bf16x8 a, bf16x8 b, floatx4 c) {
  return __builtin_amdgcn_mfma_f32_16x16x32_bf16(a, b, c, 0, 0, 0);
}

static __device__ __forceinline__ unsigned short f2b_bits(float f) {
  __bf16 h = (__bf16)f;
  return __builtin_bit_cast(unsigned short, h);
}

// async global -> LDS, 16B per lane. LDS dest is wave-uniform base + lane*16.
static __device__ __forceinline__ void stage16(const void* g, void* l) {
  __builtin_amdgcn_global_load_lds(
      (__attribute__((address_space(1))) void*)(unsigned long long)g,
      (__attribute__((address_space(3))) void*)(unsigned int)(unsigned long long)l,
      16, 0, 0);
}

// Partial-drain barrier: wait until <= N of this wave's VMEM ops outstanding,
// then block barrier. Raw asm so the compiler does NOT insert vmcnt(0).
#define WAIT_BARRIER_8() asm volatile("s_waitcnt vmcnt(8)\n\ts_barrier" ::: "memory")
#define WAIT_BARRIER_4() asm volatile("s_waitcnt vmcnt(4)\n\ts_barrier" ::: "memory")
#define WAIT_BARRIER_0() asm volatile("s_waitcnt vmcnt(0)\n\ts_barrier" ::: "memory")

// ---------------------------------------------------------------- cast + zero lsum
__global__ void cast_kernel(const float4* __restrict__ x, const float4* __restrict__ w,
                            ushort4* __restrict__ xb, ushort4* __restrict__ wb,
                            float* __restrict__ lsum) {
  int i = blockIdx.x * 256 + threadIdx.x;
  if (i < 4194304) {
    float4 v = x[i];
    ushort4 o;
    o.x = f2b_bits(v.x); o.y = f2b_bits(v.y); o.z = f2b_bits(v.z); o.w = f2b_bits(v.w);
    xb[i] = o;
  } else if (i < 4456448) {
    int j = i - 4194304;
    float4 v = w[j];
    ushort4 o;
    o.x = f2b_bits(v.x); o.y = f2b_bits(v.y); o.z = f2b_bits(v.z); o.w = f2b_bits(v.w);
    wb[j] = o;
  } else {
    int j = i - 4456448;
    if (j < 16384) lsum[j] = 0.0f;
  }
}

// Shared K-loop building blocks (4 LDS buffers, staged 2 iterations ahead).
// Each wave stages A rowgroups {2w,2w+1} and B rowgroups {2w,2w+1} (1 KB each).
#define STAGE4(buf, aoff, boff)                                   \
  do {                                                            \
    stage16(gA0 + (aoff), &lds_a[(buf)][(2 * wid + 0) * 64]);     \
    stage16(gA1 + (aoff), &lds_a[(buf)][(2 * wid + 1) * 64]);     \
    stage16(gB0 + (boff), &lds_b[(buf)][(2 * wid + 0) * 64]);     \
    stage16(gB1 + (boff), &lds_b[(buf)][(2 * wid + 1) * 64]);     \
  } while (0)

#define COMPUTE(buf)                                              \
  do {                                                            \
    bf16x8 af[4], bfr[4];                                         \
    _Pragma("unroll") for (int i_ = 0; i_ < 4; ++i_)              \
        af[i_] = lds_a[(buf)][(wr * 4 + i_) * 64 + lane];         \
    _Pragma("unroll") for (int j_ = 0; j_ < 4; ++j_)              \
        bfr[j_] = lds_b[(buf)][(wc * 4 + j_) * 64 + lane];        \
    _Pragma("unroll") for (int i_ = 0; i_ < 4; ++i_)              \
        _Pragma("unroll") for (int j_ = 0; j_ < 4; ++j_)          \
            acc[i_][j_] = mfma16(af[i_], bfr[j_], acc[i_][j_]);   \
  } while (0)

// ---------------------------------------------------------------- z^T = (x @ W^T)^T
__global__ __launch_bounds__(256, 2) void gemm_zT(const unsigned short* __restrict__ xb,
                                                  const unsigned short* __restrict__ wb,
                                                  unsigned short* __restrict__ zT) {
  __shared__ bf16x8 lds_a[4][512];
  __shared__ bf16x8 lds_b[4][512];
  const int tid = threadIdx.x, wid = tid >> 6, lane = tid & 63;
  const int wr = wid >> 1, wc = wid & 1, lr = lane & 15, lq = lane >> 4;
  const int g = blockIdx.x;
  const int xt = g & 127, yt = g >> 7;
  const int m0 = xt * 128, n0 = yt * 128;

  floatx4 acc[4][4] = {};
  const unsigned short* gA0 = xb + (m0 + (2 * wid + 0) * 16 + lr) * 1024 + lq * 8;
  const unsigned short* gA1 = xb + (m0 + (2 * wid + 1) * 16 + lr) * 1024 + lq * 8;
  const unsigned short* gB0 = wb + (n0 + (2 * wid + 0) * 16 + lr) * 1024 + lq * 8;
  const unsigned short* gB1 = wb + (n0 + (2 * wid + 1) * 16 + lr) * 1024 + lq * 8;

  STAGE4(0, 0, 0);
  STAGE4(1, 32, 32);
#pragma unroll
  for (int it = 0; it < 30; ++it) {
    const int k = (it + 2) * 32;
    STAGE4((it + 2) & 3, k, k);
    WAIT_BARRIER_8();
    COMPUTE(it & 3);
  }
  WAIT_BARRIER_4();
  COMPUTE(2);  // it=30
  WAIT_BARRIER_0();
  COMPUTE(3);  // it=31

  const int bb = m0 >> 11, sb = m0 & 2047;
#pragma unroll
  for (int i = 0; i < 4; ++i) {
    const int srow = sb + wr * 64 + i * 16 + lq * 4;
#pragma unroll
    for (int j = 0; j < 4; ++j) {
      const int n = n0 + wc * 64 + j * 16 + lr;
      ushort4 o;
      o.x = f2b_bits(acc[i][j][0]); o.y = f2b_bits(acc[i][j][1]);
      o.z = f2b_bits(acc[i][j][2]); o.w = f2b_bits(acc[i][j][3]);
      *(ushort4*)(zT + (((size_t)(bb << 10) | n) * 2048 + srow)) = o;
    }
  }
}

// ---------------------------------------------------------------- QK^T + exp epilogue
__global__ __launch_bounds__(256, 2) void qk_exp(const unsigned short* __restrict__ xb,
                                                 unsigned short* __restrict__ P,
                                                 float* __restrict__ lsum) {
  __shared__ bf16x8 lds_a[4][512];
  __shared__ bf16x8 lds_b[4][512];
  const int tid = threadIdx.x, wid = tid >> 6, lane = tid & 63;
  const int wr = wid >> 1, wc = wid & 1, lr = lane & 15, lq = lane >> 4;
  const int t = blockIdx.x, b = t & 7, idx = t >> 3;
  int mt = (int)((sqrtf(8.0f * idx + 1.0f) - 1.0f) * 0.5f);
  while ((mt + 1) * (mt + 2) / 2 <= idx) ++mt;
  while (mt * (mt + 1) / 2 > idx) --mt;
  const int nt = idx - mt * (mt + 1) / 2;
  const unsigned short* xbb = xb + (size_t)b * (2048 * 1024);
  const int q0 = mt * 128, k0t = nt * 128;

  floatx4 acc[4][4] = {};
  const unsigned short* gA0 = xbb + (q0 + (2 * wid + 0) * 16 + lr) * 1024 + lq * 8;
  const unsigned short* gA1 = xbb + (q0 + (2 * wid + 1) * 16 + lr) * 1024 + lq * 8;
  const unsigned short* gB0 = xbb + (k0t + (2 * wid + 0) * 16 + lr) * 1024 + lq * 8;
  const unsigned short* gB1 = xbb + (k0t + (2 * wid + 1) * 16 + lr) * 1024 + lq * 8;

  STAGE4(0, 0, 0);
  STAGE4(1, 32, 32);
#pragma unroll
  for (int it = 0; it < 30; ++it) {
    const int k = (it + 2) * 32;
    STAGE4((it + 2) & 3, k, k);
    WAIT_BARRIER_8();
    COMPUTE(it & 3);
  }
  WAIT_BARRIER_4();
  COMPUTE(2);
  WAIT_BARRIER_0();
  COMPUTE(3);

  unsigned short* Pt = P + ((size_t)b * 136 + (size_t)(mt * (mt + 1) / 2 + nt)) * 16384;
  const bool diag = (mt == nt);
#pragma unroll
  for (int i = 0; i < 4; ++i) {
    const int row_l = wr * 64 + i * 16 + lq * 4;
    floatx4 rs = {0.0f, 0.0f, 0.0f, 0.0f};
#pragma unroll
    for (int j = 0; j < 4; ++j) {
      const int col_l = wc * 64 + j * 16 + lr;
#pragma unroll
      for (int v = 0; v < 4; ++v) {
        float p = __expf(acc[i][j][v] * 0.03125f - 44.0f);
        if (diag && col_l > row_l + v) p = 0.0f;
        Pt[(row_l + v) * 128 + col_l] = f2b_bits(p);
        rs[v] += p;
      }
    }
#pragma unroll
    for (int v = 0; v < 4; ++v) {
      float s = rs[v];
      s += __shfl_xor(s, 1);
      s += __shfl_xor(s, 2);
      s += __shfl_xor(s, 4);
      s += __shfl_xor(s, 8);
      if (lr == 0) atomicAdd(&lsum[b * 2048 + q0 + row_l + v], s);
    }
  }
}

// ---------------------------------------------------------------- O = P @ z, divide by lsum
// Runtime trip count; LDS buffers indexed by address arithmetic (no reg-array spill).
__global__ __launch_bounds__(256, 2) void pv_out(const unsigned short* __restrict__ P,
                                                 const unsigned short* __restrict__ zT,
                                                 const float* __restrict__ lsum,
                                                 float* __restrict__ out) {
  __shared__ bf16x8 lds_a[4][512];
  __shared__ bf16x8 lds_b[4][512];
  const int tid = threadIdx.x, wid = tid >> 6, lane = tid & 63;
  const int wr = wid >> 1, wc = wid & 1, lr = lane & 15, lq = lane >> 4;
  const int g = blockIdx.x, b = g & 7, gg = g >> 3;
  const int mt = 15 - (gg >> 3), ntile = gg & 7;   // long k-loops dispatched first
  const int q0 = mt * 128, n0 = ntile * 128;
  const unsigned short* Pb = P + (size_t)b * 136 * 16384;
  const unsigned short* zTb = zT + (size_t)b * 1024 * 2048;
  const int tri = mt * (mt + 1) / 2;
  const int ktot = (mt + 1) * 4;  // BK=32 steps; multiple of 4, >= 4

  floatx4 acc[4][4] = {};
  // A (P tiles): step nk -> elem offset (nk>>2)*16384 + (nk&3)*32
  const unsigned short* gA0 = Pb + (size_t)tri * 16384 + ((2 * wid + 0) * 16 + lr) * 128 + lq * 8;
  const unsigned short* gA1 = Pb + (size_t)tri * 16384 + ((2 * wid + 1) * 16 + lr) * 128 + lq * 8;
  // B (zT): step nk -> elem offset nk*32
  const unsigned short* gB0 = zTb + (n0 + (2 * wid + 0) * 16 + lr) * 2048 + lq * 8;
  const unsigned short* gB1 = zTb + (n0 + (2 * wid + 1) * 16 + lr) * 2048 + lq * 8;

#define PV_AOFF(nk) (((nk) >> 2) * 16384 + ((nk) & 3) * 32)
  STAGE4(0, PV_AOFF(0), 0);
  STAGE4(1, PV_AOFF(1), 32);
  for (int kk = 0; kk + 2 < ktot; ++kk) {
    const int nk = kk + 2;
    STAGE4(nk & 3, PV_AOFF(nk), nk * 32);
    WAIT_BARRIER_8();
    COMPUTE(kk & 3);
  }
  WAIT_BARRIER_4();
  COMPUTE((ktot - 2) & 3);
  WAIT_BARRIER_0();
  COMPUTE((ktot - 1) & 3);

  float* outb = out + (size_t)b * 2048 * 1024;
#pragma unroll
  for (int i = 0; i < 4; ++i) {
    const int row_l = wr * 64 + i * 16 + lq * 4;
    floatx4 linv;
#pragma unroll
    for (int v = 0; v < 4; ++v) linv[v] = 1.0f / lsum[b * 2048 + q0 + row_l + v];
#pragma unroll
    for (int j = 0; j < 4; ++j) {
      const int col = n0 + wc * 64 + j * 16 + lr;
#pragma unroll
      for (int v = 0; v < 4; ++v)
        outb[(size_t)(q0 + row_l + v) * 1024 + col] = acc[i][j][v] * linv[v];
    }
  }
}

// ---------------------------------------------------------------- launcher
extern "C" void kernel_launch(void* const* d_in, const int* in_sizes, int n_in,
                              void* d_out, int out_size, void* d_ws, size_t ws_size,
                              hipStream_t stream) {
  const float* x = (const float*)d_in[0];  // [8][2048][1024]
  const float* W = (const float*)d_in[1];  // [1024][1024]
  float* out = (float*)d_out;              // [8][2048][1024]
  char* ws = (char*)d_ws;
  unsigned short* xb = (unsigned short*)ws;                          // 32 MiB bf16 x
  unsigned short* zT = (unsigned short*)(ws + 33554432ull);          // 32 MiB bf16 z^T
  unsigned short* P  = (unsigned short*)(ws + 67108864ull);          // 34 MiB packed tri P
  unsigned short* wb = P;  // alias: wb consumed by gemm_zT before P is written
  float* lsum = (float*)(ws + 67108864ull + 35651584ull);            // 64 KiB row sums

  cast_kernel<<<17472, 256, 0, stream>>>((const float4*)x, (const float4*)W,
                                         (ushort4*)xb, (ushort4*)wb, lsum);
  gemm_zT<<<1024, 256, 0, stream>>>(xb, wb, zT);
  qk_exp<<<1088, 256, 0, stream>>>(xb, P, lsum);
  pv_out<<<1024, 256, 0, stream>>>(P, zT, lsum, out);
}